// Round 1
// baseline (1389.709 us; speedup 1.0000x reference)
//
#include <hip/hip_runtime.h>

#define D 64
#define LAYERS 3

// ---------------- CSR build ----------------

__global__ void k_count(const int* __restrict__ dst, int* __restrict__ cnt, int E) {
    int e = blockIdx.x * blockDim.x + threadIdx.x;
    if (e < E) atomicAdd(&cnt[dst[e]], 1);
}

__global__ __launch_bounds__(1024) void k_scan(const int* __restrict__ cnt,
                                               int* __restrict__ row_start,
                                               float* __restrict__ inv_deg, int N) {
    __shared__ int buf[1024];
    int tid = threadIdx.x;
    int per = (N + 1023) >> 10;
    int begin = tid * per;
    int end = min(begin + per, N);
    int s = 0;
    for (int i = begin; i < end; i++) s += cnt[i];
    buf[tid] = s;
    __syncthreads();
    // inclusive Hillis-Steele scan
    for (int off = 1; off < 1024; off <<= 1) {
        int v = 0;
        if (tid >= off) v = buf[tid - off];
        __syncthreads();
        buf[tid] += v;
        __syncthreads();
    }
    int run = buf[tid] - s;  // exclusive prefix of this chunk
    for (int i = begin; i < end; i++) {
        row_start[i] = run;
        int c = cnt[i];
        inv_deg[i] = 1.0f / (float)(c > 1 ? c : 1);
        run += c;
    }
    if (begin < N && end == N) row_start[N] = run;
}

__global__ void k_fill(const int* __restrict__ src, const int* __restrict__ dst,
                       const int* __restrict__ row_start, int* __restrict__ cursor,
                       int* __restrict__ eids, int* __restrict__ srcs, int E) {
    int e = blockIdx.x * blockDim.x + threadIdx.x;
    if (e >= E) return;
    int d = dst[e];
    int p = row_start[d] + atomicAdd(&cursor[d], 1);
    eids[p] = e;
    srcs[p] = src[e];
}

// ---------------- aggregation: Sx[n] = sum x[src], Se[n] = sum ea[e] ----------------
// block (64,4): one wave per node, lane = feature
__global__ __launch_bounds__(256) void k_agg(const float* __restrict__ x,
                                             const float* __restrict__ ea,
                                             const int* __restrict__ row_start,
                                             const int* __restrict__ eids,
                                             const int* __restrict__ srcs,
                                             float* __restrict__ Sx, float* __restrict__ Se,
                                             int N) {
    int n = blockIdx.x * 4 + threadIdx.y;
    if (n >= N) return;
    int j = threadIdx.x;
    int p0 = row_start[n], p1 = row_start[n + 1];
    float ax = 0.f, ae = 0.f;
    for (int p = p0; p < p1; p++) {
        int e = eids[p];
        int s = srcs[p];
        ax += x[(size_t)s * D + j];
        ae += ea[(size_t)e * D + j];
    }
    Sx[(size_t)n * D + j] = ax;
    Se[(size_t)n * D + j] = ae;
}

// ---------------- node update: xo = [relu](x@Wr + inv*(Sx@Wn + Se@We) + b) ----------------
__global__ __launch_bounds__(256) void k_node(const float* __restrict__ x,
                                              const float* __restrict__ Sx,
                                              const float* __restrict__ Se,
                                              const float* __restrict__ inv_deg,
                                              const float* __restrict__ Wr,
                                              const float* __restrict__ Wn,
                                              const float* __restrict__ We,
                                              const float* __restrict__ bias,
                                              float* __restrict__ xo, int N, int do_relu) {
    __shared__ float sWr[D * D], sWn[D * D], sWe[D * D];
    __shared__ float rx[4][D], rsx[4][D], rse[4][D];
    int tid = threadIdx.y * 64 + threadIdx.x;
    for (int i = tid; i < D * D; i += 256) {
        sWr[i] = Wr[i];
        sWn[i] = Wn[i];
        sWe[i] = We[i];
    }
    int j = threadIdx.x;
    int ty = threadIdx.y;
    float bj = bias[j];
    for (int g = blockIdx.x; g * 4 < N; g += gridDim.x) {
        int n = g * 4 + ty;
        __syncthreads();
        if (n < N) {
            rx[ty][j]  = x[(size_t)n * D + j];
            rsx[ty][j] = Sx[(size_t)n * D + j];
            rse[ty][j] = Se[(size_t)n * D + j];
        }
        __syncthreads();
        if (n < N) {
            float inv = inv_deg[n];
            float a0 = 0.f, a1 = 0.f, a2 = 0.f;
            #pragma unroll 8
            for (int k = 0; k < D; k++) {
                float xv = rx[ty][k];
                float sv = rsx[ty][k];
                float ev = rse[ty][k];
                a0 += xv * sWr[k * D + j];
                a1 += sv * sWn[k * D + j];
                a2 += ev * sWe[k * D + j];
            }
            float v = a0 + inv * (a1 + a2) + bj;
            xo[(size_t)n * D + j] = do_relu ? fmaxf(v, 0.f) : v;
        }
    }
}

// ---------------- s/t features: sf = x@Ws + bs, tf = x@Wt + bt ----------------
__global__ __launch_bounds__(256) void k_st(const float* __restrict__ x,
                                            const float* __restrict__ Ws, const float* __restrict__ bs,
                                            const float* __restrict__ Wt, const float* __restrict__ bt,
                                            float* __restrict__ sf, float* __restrict__ tf, int N) {
    __shared__ float sWs[D * D], sWt[D * D];
    __shared__ float rx[4][D];
    int tid = threadIdx.y * 64 + threadIdx.x;
    for (int i = tid; i < D * D; i += 256) {
        sWs[i] = Ws[i];
        sWt[i] = Wt[i];
    }
    int j = threadIdx.x;
    int ty = threadIdx.y;
    float bsj = bs[j], btj = bt[j];
    for (int g = blockIdx.x; g * 4 < N; g += gridDim.x) {
        int n = g * 4 + ty;
        __syncthreads();
        if (n < N) rx[ty][j] = x[(size_t)n * D + j];
        __syncthreads();
        if (n < N) {
            float a0 = 0.f, a1 = 0.f;
            #pragma unroll 8
            for (int k = 0; k < D; k++) {
                float xv = rx[ty][k];
                a0 += xv * sWs[k * D + j];
                a1 += xv * sWt[k * D + j];
            }
            sf[(size_t)n * D + j] = a0 + bsj;
            tf[(size_t)n * D + j] = a1 + btj;
        }
    }
}

// ---------------- edge MLP: ea_out = relu(ea@We + be + sf[src] + tf[dst]) @ W1 + b1 ----------------
// block 256 = 16 edges x 16 feature-quads
__global__ __launch_bounds__(256) void k_edge(const float* __restrict__ ea_in,
                                              const int* __restrict__ src,
                                              const int* __restrict__ dstv,
                                              const float* __restrict__ sf,
                                              const float* __restrict__ tf,
                                              const float* __restrict__ We,
                                              const float* __restrict__ be,
                                              const float* __restrict__ W1,
                                              const float* __restrict__ b1,
                                              float* __restrict__ ea_out, int E) {
    __shared__ float sWe[D * D], sW1[D * D];
    __shared__ float eas[16][D + 4];
    __shared__ float rs[16][D + 4];
    int tid = threadIdx.x;
    int tx = tid & 15, ty = tid >> 4;
    for (int i = tid; i < D * D; i += 256) {
        sWe[i] = We[i];
        sW1[i] = W1[i];
    }
    int j0 = tx * 4;
    float4 bev = *(const float4*)&be[j0];
    float4 b1v = *(const float4*)&b1[j0];
    for (long long base = (long long)blockIdx.x * 16; base < E; base += (long long)gridDim.x * 16) {
        int e = (int)base + ty;
        __syncthreads();
        if (e < E) {
            float4 v = *(const float4*)&ea_in[(size_t)e * D + j0];
            *(float4*)&eas[ty][j0] = v;
        }
        __syncthreads();
        if (e < E) {
            int s = src[e], d = dstv[e];
            float4 sg = *(const float4*)&sf[(size_t)s * D + j0];
            float4 tg = *(const float4*)&tf[(size_t)d * D + j0];
            float h0 = bev.x + sg.x + tg.x;
            float h1 = bev.y + sg.y + tg.y;
            float h2 = bev.z + sg.z + tg.z;
            float h3 = bev.w + sg.w + tg.w;
            #pragma unroll 8
            for (int k = 0; k < D; k++) {
                float a = eas[ty][k];
                float4 w = *(const float4*)&sWe[k * D + j0];
                h0 += a * w.x;
                h1 += a * w.y;
                h2 += a * w.z;
                h3 += a * w.w;
            }
            rs[ty][j0 + 0] = fmaxf(h0, 0.f);
            rs[ty][j0 + 1] = fmaxf(h1, 0.f);
            rs[ty][j0 + 2] = fmaxf(h2, 0.f);
            rs[ty][j0 + 3] = fmaxf(h3, 0.f);
        }
        __syncthreads();
        if (e < E) {
            float o0 = b1v.x, o1 = b1v.y, o2 = b1v.z, o3 = b1v.w;
            #pragma unroll 8
            for (int k = 0; k < D; k++) {
                float a = rs[ty][k];
                float4 w = *(const float4*)&sW1[k * D + j0];
                o0 += a * w.x;
                o1 += a * w.y;
                o2 += a * w.z;
                o3 += a * w.w;
            }
            float4 o = make_float4(o0, o1, o2, o3);
            *(float4*)&ea_out[(size_t)e * D + j0] = o;
        }
    }
}

extern "C" void kernel_launch(void* const* d_in, const int* in_sizes, int n_in,
                              void* d_out, int out_size, void* d_ws, size_t ws_size,
                              hipStream_t stream) {
    const float* x0  = (const float*)d_in[0];
    const int*   ei  = (const int*)d_in[1];
    const float* ea0 = (const float*)d_in[2];
    const float* Wr  = (const float*)d_in[3];
    const float* Wn  = (const float*)d_in[4];
    const float* We  = (const float*)d_in[5];
    const float* b   = (const float*)d_in[6];
    const float* EWe = (const float*)d_in[7];
    const float* Ebe = (const float*)d_in[8];
    const float* EWs = (const float*)d_in[9];
    const float* Ebs = (const float*)d_in[10];
    const float* EWt = (const float*)d_in[11];
    const float* Ebt = (const float*)d_in[12];
    const float* EW1 = (const float*)d_in[13];
    const float* Eb1 = (const float*)d_in[14];

    const int N = in_sizes[0] / D;
    const int E = in_sizes[1] / 2;
    const int* src = ei;
    const int* dst = ei + E;

    char* ws = (char*)d_ws;
    size_t off = 0;
    auto alloc = [&](size_t bytes) {
        void* p = ws + off;
        off += (bytes + 255) & ~(size_t)255;
        return p;
    };
    int*   cnt       = (int*)alloc((size_t)N * 4);
    int*   cursor    = (int*)alloc((size_t)N * 4);
    int*   row_start = (int*)alloc((size_t)(N + 1) * 4);
    int*   eids      = (int*)alloc((size_t)E * 4);
    int*   srcs      = (int*)alloc((size_t)E * 4);
    float* inv_deg   = (float*)alloc((size_t)N * 4);
    float* Sx        = (float*)alloc((size_t)N * D * 4);
    float* Se        = (float*)alloc((size_t)N * D * 4);
    float* x1        = (float*)alloc((size_t)N * D * 4);
    float* x2        = (float*)alloc((size_t)N * D * 4);
    // s/t features alias Sx/Se: Sx/Se are dead after k_node, sf/tf dead after k_edge,
    // and the next k_agg rewrites them. Stream order serializes all of it.
    float* sf = Sx;
    float* tf = Se;

    float* outx  = (float*)d_out;
    float* outea = (float*)d_out + (size_t)N * D;

    hipMemsetAsync(cnt, 0, (size_t)N * 4, stream);
    hipMemsetAsync(cursor, 0, (size_t)N * 4, stream);
    k_count<<<(E + 255) / 256, 256, 0, stream>>>(dst, cnt, E);
    k_scan<<<1, 1024, 0, stream>>>(cnt, row_start, inv_deg, N);
    k_fill<<<(E + 255) / 256, 256, 0, stream>>>(src, dst, row_start, cursor, eids, srcs, E);

    const float* xc  = x0;
    const float* eac = ea0;
    float* xbufs[3] = {x1, x2, outx};
    dim3 b644(64, 4);

    for (int i = 0; i < LAYERS; i++) {
        k_agg<<<(N + 3) / 4, b644, 0, stream>>>(xc, eac, row_start, eids, srcs, Sx, Se, N);
        float* xn = xbufs[i];
        k_node<<<2048, b644, 0, stream>>>(xc, Sx, Se, inv_deg,
                                          Wr + (size_t)i * D * D, Wn + (size_t)i * D * D,
                                          We + (size_t)i * D * D, b + (size_t)i * D,
                                          xn, N, (i < LAYERS - 1) ? 1 : 0);
        if (i < LAYERS - 1) {
            k_st<<<2048, b644, 0, stream>>>(xn, EWs + (size_t)i * D * D, Ebs + (size_t)i * D,
                                            EWt + (size_t)i * D * D, Ebt + (size_t)i * D,
                                            sf, tf, N);
            k_edge<<<4096, 256, 0, stream>>>(eac, src, dst, sf, tf,
                                             EWe + (size_t)i * D * D, Ebe + (size_t)i * D,
                                             EW1 + (size_t)i * D * D, Eb1 + (size_t)i * D,
                                             outea, E);
            eac = outea;
        }
        xc = xn;
    }
}

// Round 2
// 1061.552 us; speedup vs baseline: 1.3091x; 1.3091x over previous
//
#include <hip/hip_runtime.h>

#define D 64
#define LAYERS 3

typedef float  f4  __attribute__((ext_vector_type(4)));
typedef short  s8v __attribute__((ext_vector_type(8)));

__device__ __forceinline__ unsigned short f2bf(float x) {
    unsigned int u = __float_as_uint(x);
    unsigned int r = (u + 0x7fffu + ((u >> 16) & 1u)) >> 16;
    return (unsigned short)r;
}
__device__ __forceinline__ float bf2f(unsigned short h) {
    return __uint_as_float(((unsigned int)h) << 16);
}

// ---------------- CSR build ----------------

__global__ void k_count(const int* __restrict__ dst, int* __restrict__ cnt, int E) {
    int e = blockIdx.x * blockDim.x + threadIdx.x;
    if (e < E) atomicAdd(&cnt[dst[e]], 1);
}

__global__ __launch_bounds__(1024) void k_scan(const int* __restrict__ cnt,
                                               int* __restrict__ row_start,
                                               float* __restrict__ inv_deg, int N) {
    __shared__ int buf[1024];
    int tid = threadIdx.x;
    int per = (N + 1023) >> 10;
    int begin = tid * per;
    int end = min(begin + per, N);
    int s = 0;
    for (int i = begin; i < end; i++) s += cnt[i];
    buf[tid] = s;
    __syncthreads();
    for (int off = 1; off < 1024; off <<= 1) {
        int v = 0;
        if (tid >= off) v = buf[tid - off];
        __syncthreads();
        buf[tid] += v;
        __syncthreads();
    }
    int run = buf[tid] - s;
    for (int i = begin; i < end; i++) {
        row_start[i] = run;
        int c = cnt[i];
        inv_deg[i] = 1.0f / (float)(c > 1 ? c : 1);
        run += c;
    }
    if (begin < N && end == N) row_start[N] = run;
}

__global__ void k_fill(const int* __restrict__ src, const int* __restrict__ dst,
                       const int* __restrict__ row_start, int* __restrict__ cursor,
                       int* __restrict__ eids, int* __restrict__ srcs, int E) {
    int e = blockIdx.x * blockDim.x + threadIdx.x;
    if (e >= E) return;
    int d = dst[e];
    int p = row_start[d] + atomicAdd(&cursor[d], 1);
    eids[p] = e;
    srcs[p] = src[e];
}

// ---------------- aggregation ----------------
__global__ __launch_bounds__(256) void k_agg(const float* __restrict__ x,
                                             const float* __restrict__ ea,
                                             const int* __restrict__ row_start,
                                             const int* __restrict__ eids,
                                             const int* __restrict__ srcs,
                                             float* __restrict__ Sx, float* __restrict__ Se,
                                             int N) {
    int n = blockIdx.x * 4 + threadIdx.y;
    if (n >= N) return;
    int j = threadIdx.x;
    int p0 = row_start[n], p1 = row_start[n + 1];
    float ax = 0.f, ae = 0.f;
    for (int p = p0; p < p1; p++) {
        int e = eids[p];
        int s = srcs[p];
        ax += x[(size_t)s * D + j];
        ae += ea[(size_t)e * D + j];
    }
    Sx[(size_t)n * D + j] = ax;
    Se[(size_t)n * D + j] = ae;
}

// ---------------- node update ----------------
__global__ __launch_bounds__(256) void k_node(const float* __restrict__ x,
                                              const float* __restrict__ Sx,
                                              const float* __restrict__ Se,
                                              const float* __restrict__ inv_deg,
                                              const float* __restrict__ Wr,
                                              const float* __restrict__ Wn,
                                              const float* __restrict__ We,
                                              const float* __restrict__ bias,
                                              float* __restrict__ xo, int N, int do_relu) {
    __shared__ float sWr[D * D], sWn[D * D], sWe[D * D];
    __shared__ float rx[4][D], rsx[4][D], rse[4][D];
    int tid = threadIdx.y * 64 + threadIdx.x;
    for (int i = tid; i < D * D; i += 256) {
        sWr[i] = Wr[i];
        sWn[i] = Wn[i];
        sWe[i] = We[i];
    }
    int j = threadIdx.x;
    int ty = threadIdx.y;
    float bj = bias[j];
    for (int g = blockIdx.x; g * 4 < N; g += gridDim.x) {
        int n = g * 4 + ty;
        __syncthreads();
        if (n < N) {
            rx[ty][j]  = x[(size_t)n * D + j];
            rsx[ty][j] = Sx[(size_t)n * D + j];
            rse[ty][j] = Se[(size_t)n * D + j];
        }
        __syncthreads();
        if (n < N) {
            float inv = inv_deg[n];
            float a0 = 0.f, a1 = 0.f, a2 = 0.f;
            #pragma unroll 8
            for (int k = 0; k < D; k++) {
                float xv = rx[ty][k];
                float sv = rsx[ty][k];
                float ev = rse[ty][k];
                a0 += xv * sWr[k * D + j];
                a1 += sv * sWn[k * D + j];
                a2 += ev * sWe[k * D + j];
            }
            float v = a0 + inv * (a1 + a2) + bj;
            xo[(size_t)n * D + j] = do_relu ? fmaxf(v, 0.f) : v;
        }
    }
}

// ---------------- s/t features ----------------
__global__ __launch_bounds__(256) void k_st(const float* __restrict__ x,
                                            const float* __restrict__ Ws, const float* __restrict__ bs,
                                            const float* __restrict__ Wt, const float* __restrict__ bt,
                                            float* __restrict__ sf, float* __restrict__ tf, int N) {
    __shared__ float sWs[D * D], sWt[D * D];
    __shared__ float rx[4][D];
    int tid = threadIdx.y * 64 + threadIdx.x;
    for (int i = tid; i < D * D; i += 256) {
        sWs[i] = Ws[i];
        sWt[i] = Wt[i];
    }
    int j = threadIdx.x;
    int ty = threadIdx.y;
    float bsj = bs[j], btj = bt[j];
    for (int g = blockIdx.x; g * 4 < N; g += gridDim.x) {
        int n = g * 4 + ty;
        __syncthreads();
        if (n < N) rx[ty][j] = x[(size_t)n * D + j];
        __syncthreads();
        if (n < N) {
            float a0 = 0.f, a1 = 0.f;
            #pragma unroll 8
            for (int k = 0; k < D; k++) {
                float xv = rx[ty][k];
                a0 += xv * sWs[k * D + j];
                a1 += xv * sWt[k * D + j];
            }
            sf[(size_t)n * D + j] = a0 + bsj;
            tf[(size_t)n * D + j] = a1 + btj;
        }
    }
}

// ---------------- edge MLP via MFMA (transposed-operand formulation) ----------------
// Computes h^T = We^T @ ea^T and out^T = W1^T @ h^T with mfma_f32_16x16x32_bf16.
// D-frag: col = lane&15 = EDGE, row = 4*(lane>>4)+r = feature index.
// GEMM1 D-frag feeds GEMM2 B-frag directly in registers via k-permutation
// pi(kt,g,i) = 32*kt + 16*(i>>2) + 4*g + (i&3) baked into W1's A-frag prepack.
// We split hi+lo bf16 (removes weight-rounding error); W1 plain bf16.
__global__ __launch_bounds__(256, 2) void k_edge_mfma(
        const float* __restrict__ ea_in,
        const int* __restrict__ src, const int* __restrict__ dstv,
        const float* __restrict__ sf, const float* __restrict__ tf,
        const float* __restrict__ We, const float* __restrict__ be,
        const float* __restrict__ W1, const float* __restrict__ b1,
        float* __restrict__ ea_out, int E) {
    int lane = threadIdx.x & 63;
    int wid  = threadIdx.x >> 6;
    int c = lane & 15;      // edge slot within tile / A-row
    int g = lane >> 4;      // k-group

    // ---- preload weight fragments into registers ----
    s8v weh[4][2], wel[4][2], w1f[4][2];
    #pragma unroll
    for (int nt = 0; nt < 4; nt++) {
        #pragma unroll
        for (int kt = 0; kt < 2; kt++) {
            #pragma unroll
            for (int i = 0; i < 8; i++) {
                int k = 32 * kt + 8 * g + i;            // natural k-order (GEMM1)
                float w = We[k * D + 16 * nt + c];
                unsigned short hb = f2bf(w);
                float hf = bf2f(hb);
                unsigned short lb = f2bf(w - hf);
                weh[nt][kt][i] = (short)hb;
                wel[nt][kt][i] = (short)lb;
            }
            #pragma unroll
            for (int i = 0; i < 8; i++) {
                int k = 32 * kt + 16 * (i >> 2) + 4 * g + (i & 3);  // pi-order (GEMM2)
                w1f[nt][kt][i] = (short)f2bf(W1[k * D + 16 * nt + c]);
            }
        }
    }
    // biases at this lane's D-frag rows n = 16*nt + 4*g + r
    f4 bev[4], b1v[4];
    #pragma unroll
    for (int nt = 0; nt < 4; nt++) {
        bev[nt] = *(const f4*)&be[16 * nt + 4 * g];
        b1v[nt] = *(const f4*)&b1[16 * nt + 4 * g];
    }

    int tiles = (E + 15) >> 4;
    for (int t = blockIdx.x * 4 + wid; t < tiles; t += gridDim.x * 4) {
        int e = t * 16 + c;
        int ec = e < E ? e : E - 1;
        const float* ear = ea_in + (size_t)ec * D;

        // B-frags of GEMM1: lane's own edge row, natural k-order
        s8v eaf[2];
        #pragma unroll
        for (int kt = 0; kt < 2; kt++) {
            f4 a0 = *(const f4*)&ear[32 * kt + 8 * g];
            f4 a1 = *(const f4*)&ear[32 * kt + 8 * g + 4];
            #pragma unroll
            for (int i = 0; i < 4; i++) {
                eaf[kt][i]     = (short)f2bf(a0[i]);
                eaf[kt][4 + i] = (short)f2bf(a1[i]);
            }
        }

        // GEMM1: h^T = We^T ea^T  (hi + lo products)
        f4 acc[4];
        #pragma unroll
        for (int nt = 0; nt < 4; nt++) acc[nt] = (f4){0.f, 0.f, 0.f, 0.f};
        #pragma unroll
        for (int nt = 0; nt < 4; nt++) {
            #pragma unroll
            for (int kt = 0; kt < 2; kt++) {
                acc[nt] = __builtin_amdgcn_mfma_f32_16x16x32_bf16(weh[nt][kt], eaf[kt], acc[nt], 0, 0, 0);
                acc[nt] = __builtin_amdgcn_mfma_f32_16x16x32_bf16(wel[nt][kt], eaf[kt], acc[nt], 0, 0, 0);
            }
        }

        // epilogue 1: + be + sf[src] + tf[dst], relu, convert to GEMM2 B-frags
        int s = src[ec], d = dstv[ec];
        const float* sr = sf + (size_t)s * D;
        const float* tr = tf + (size_t)d * D;
        s8v hf[2];
        #pragma unroll
        for (int nt = 0; nt < 4; nt++) {
            f4 sg = *(const f4*)&sr[16 * nt + 4 * g];
            f4 tg = *(const f4*)&tr[16 * nt + 4 * g];
            f4 h = acc[nt] + bev[nt] + sg + tg;
            #pragma unroll
            for (int r = 0; r < 4; r++) {
                float hv = fmaxf(h[r], 0.f);
                hf[nt >> 1][((nt & 1) << 2) + r] = (short)f2bf(hv);
            }
        }

        // GEMM2: out^T = W1^T h^T  (pi-order on both sides)
        f4 out[4];
        #pragma unroll
        for (int nt = 0; nt < 4; nt++) out[nt] = (f4){0.f, 0.f, 0.f, 0.f};
        #pragma unroll
        for (int nt = 0; nt < 4; nt++) {
            #pragma unroll
            for (int kt = 0; kt < 2; kt++) {
                out[nt] = __builtin_amdgcn_mfma_f32_16x16x32_bf16(w1f[nt][kt], hf[kt], out[nt], 0, 0, 0);
            }
        }

        if (e < E) {
            float* orow = ea_out + (size_t)e * D;
            #pragma unroll
            for (int nt = 0; nt < 4; nt++) {
                f4 o = out[nt] + b1v[nt];
                *(f4*)&orow[16 * nt + 4 * g] = o;
            }
        }
    }
}

extern "C" void kernel_launch(void* const* d_in, const int* in_sizes, int n_in,
                              void* d_out, int out_size, void* d_ws, size_t ws_size,
                              hipStream_t stream) {
    const float* x0  = (const float*)d_in[0];
    const int*   ei  = (const int*)d_in[1];
    const float* ea0 = (const float*)d_in[2];
    const float* Wr  = (const float*)d_in[3];
    const float* Wn  = (const float*)d_in[4];
    const float* We  = (const float*)d_in[5];
    const float* b   = (const float*)d_in[6];
    const float* EWe = (const float*)d_in[7];
    const float* Ebe = (const float*)d_in[8];
    const float* EWs = (const float*)d_in[9];
    const float* Ebs = (const float*)d_in[10];
    const float* EWt = (const float*)d_in[11];
    const float* Ebt = (const float*)d_in[12];
    const float* EW1 = (const float*)d_in[13];
    const float* Eb1 = (const float*)d_in[14];

    const int N = in_sizes[0] / D;
    const int E = in_sizes[1] / 2;
    const int* src = ei;
    const int* dst = ei + E;

    char* ws = (char*)d_ws;
    size_t off = 0;
    auto alloc = [&](size_t bytes) {
        void* p = ws + off;
        off += (bytes + 255) & ~(size_t)255;
        return p;
    };
    int*   cnt       = (int*)alloc((size_t)N * 4);
    int*   cursor    = (int*)alloc((size_t)N * 4);
    int*   row_start = (int*)alloc((size_t)(N + 1) * 4);
    int*   eids      = (int*)alloc((size_t)E * 4);
    int*   srcs      = (int*)alloc((size_t)E * 4);
    float* inv_deg   = (float*)alloc((size_t)N * 4);
    float* Sx        = (float*)alloc((size_t)N * D * 4);
    float* Se        = (float*)alloc((size_t)N * D * 4);
    float* x1        = (float*)alloc((size_t)N * D * 4);
    float* x2        = (float*)alloc((size_t)N * D * 4);
    float* sf = Sx;  // alias: Sx/Se dead after k_node, sf/tf dead after k_edge
    float* tf = Se;

    float* outx  = (float*)d_out;
    float* outea = (float*)d_out + (size_t)N * D;

    hipMemsetAsync(cnt, 0, (size_t)N * 4, stream);
    hipMemsetAsync(cursor, 0, (size_t)N * 4, stream);
    k_count<<<(E + 255) / 256, 256, 0, stream>>>(dst, cnt, E);
    k_scan<<<1, 1024, 0, stream>>>(cnt, row_start, inv_deg, N);
    k_fill<<<(E + 255) / 256, 256, 0, stream>>>(src, dst, row_start, cursor, eids, srcs, E);

    const float* xc  = x0;
    const float* eac = ea0;
    float* xbufs[3] = {x1, x2, outx};
    dim3 b644(64, 4);

    for (int i = 0; i < LAYERS; i++) {
        k_agg<<<(N + 3) / 4, b644, 0, stream>>>(xc, eac, row_start, eids, srcs, Sx, Se, N);
        float* xn = xbufs[i];
        k_node<<<2048, b644, 0, stream>>>(xc, Sx, Se, inv_deg,
                                          Wr + (size_t)i * D * D, Wn + (size_t)i * D * D,
                                          We + (size_t)i * D * D, b + (size_t)i * D,
                                          xn, N, (i < LAYERS - 1) ? 1 : 0);
        if (i < LAYERS - 1) {
            k_st<<<2048, b644, 0, stream>>>(xn, EWs + (size_t)i * D * D, Ebs + (size_t)i * D,
                                            EWt + (size_t)i * D * D, Ebt + (size_t)i * D,
                                            sf, tf, N);
            k_edge_mfma<<<512, 256, 0, stream>>>(eac, src, dst, sf, tf,
                                                 EWe + (size_t)i * D * D, Ebe + (size_t)i * D,
                                                 EW1 + (size_t)i * D * D, Eb1 + (size_t)i * D,
                                                 outea, E);
            eac = outea;
        }
        xc = xn;
    }
}

// Round 3
// 973.699 us; speedup vs baseline: 1.4272x; 1.0902x over previous
//
#include <hip/hip_runtime.h>

#define D 64
#define LAYERS 3

typedef float  f4  __attribute__((ext_vector_type(4)));
typedef short  s8v __attribute__((ext_vector_type(8)));

__device__ __forceinline__ unsigned short f2bf(float x) {
    unsigned int u = __float_as_uint(x);
    unsigned int r = (u + 0x7fffu + ((u >> 16) & 1u)) >> 16;
    return (unsigned short)r;
}
__device__ __forceinline__ float bf2f(unsigned short h) {
    return __uint_as_float(((unsigned int)h) << 16);
}

// ---------------- CSR build ----------------

__global__ void k_count(const int* __restrict__ dst, int* __restrict__ cnt, int E) {
    int e = blockIdx.x * blockDim.x + threadIdx.x;
    if (e < E) atomicAdd(&cnt[dst[e]], 1);
}

__global__ __launch_bounds__(1024) void k_scan(const int* __restrict__ cnt,
                                               int* __restrict__ row_start,
                                               float* __restrict__ inv_deg, int N) {
    __shared__ int buf[1024];
    int tid = threadIdx.x;
    int per = (N + 1023) >> 10;
    int begin = tid * per;
    int end = min(begin + per, N);
    int s = 0;
    for (int i = begin; i < end; i++) s += cnt[i];
    buf[tid] = s;
    __syncthreads();
    for (int off = 1; off < 1024; off <<= 1) {
        int v = 0;
        if (tid >= off) v = buf[tid - off];
        __syncthreads();
        buf[tid] += v;
        __syncthreads();
    }
    int run = buf[tid] - s;
    for (int i = begin; i < end; i++) {
        row_start[i] = run;
        int c = cnt[i];
        inv_deg[i] = 1.0f / (float)(c > 1 ? c : 1);
        run += c;
    }
    if (begin < N && end == N) row_start[N] = run;
}

// fill CSR; also pdst[p] = dst node of slot p, pos[e] = CSR slot of edge e
__global__ void k_fill(const int* __restrict__ src, const int* __restrict__ dst,
                       const int* __restrict__ row_start, int* __restrict__ cursor,
                       int* __restrict__ eids, int* __restrict__ srcs,
                       int* __restrict__ pdst, int* __restrict__ pos, int E) {
    int e = blockIdx.x * blockDim.x + threadIdx.x;
    if (e >= E) return;
    int d = dst[e];
    int p = row_start[d] + atomicAdd(&cursor[d], 1);
    eids[p] = e;
    srcs[p] = src[e];
    pdst[p] = d;
    pos[e] = p;
}

// ---------------- aggregation, layer 0: gather ea by eids ----------------
__global__ __launch_bounds__(256) void k_agg_gather(const float* __restrict__ x,
                                                    const float* __restrict__ ea,
                                                    const int* __restrict__ row_start,
                                                    const int* __restrict__ eids,
                                                    const int* __restrict__ srcs,
                                                    float* __restrict__ Sx, float* __restrict__ Se,
                                                    int N) {
    int n = blockIdx.x * 4 + threadIdx.y;
    if (n >= N) return;
    int j = threadIdx.x;
    int p0 = row_start[n], p1 = row_start[n + 1];
    float ax0 = 0.f, ax1 = 0.f, ax2 = 0.f, ax3 = 0.f;
    float ae0 = 0.f, ae1 = 0.f, ae2 = 0.f, ae3 = 0.f;
    int p = p0;
    for (; p + 4 <= p1; p += 4) {
        int s0 = srcs[p], s1 = srcs[p + 1], s2 = srcs[p + 2], s3 = srcs[p + 3];
        int e0 = eids[p], e1 = eids[p + 1], e2 = eids[p + 2], e3 = eids[p + 3];
        ax0 += x[(size_t)s0 * D + j];
        ax1 += x[(size_t)s1 * D + j];
        ax2 += x[(size_t)s2 * D + j];
        ax3 += x[(size_t)s3 * D + j];
        ae0 += ea[(size_t)e0 * D + j];
        ae1 += ea[(size_t)e1 * D + j];
        ae2 += ea[(size_t)e2 * D + j];
        ae3 += ea[(size_t)e3 * D + j];
    }
    for (; p < p1; p++) {
        ax0 += x[(size_t)srcs[p] * D + j];
        ae0 += ea[(size_t)eids[p] * D + j];
    }
    Sx[(size_t)n * D + j] = (ax0 + ax1) + (ax2 + ax3);
    Se[(size_t)n * D + j] = (ae0 + ae1) + (ae2 + ae3);
}

// ---------------- aggregation, layers 1/2: ea already CSR-permuted (streaming) ----------------
__global__ __launch_bounds__(256) void k_agg_seq(const float* __restrict__ x,
                                                 const float* __restrict__ pea,
                                                 const int* __restrict__ row_start,
                                                 const int* __restrict__ srcs,
                                                 float* __restrict__ Sx, float* __restrict__ Se,
                                                 int N) {
    int n = blockIdx.x * 4 + threadIdx.y;
    if (n >= N) return;
    int j = threadIdx.x;
    int p0 = row_start[n], p1 = row_start[n + 1];
    float ax0 = 0.f, ax1 = 0.f, ax2 = 0.f, ax3 = 0.f;
    float ae0 = 0.f, ae1 = 0.f, ae2 = 0.f, ae3 = 0.f;
    int p = p0;
    for (; p + 4 <= p1; p += 4) {
        int s0 = srcs[p], s1 = srcs[p + 1], s2 = srcs[p + 2], s3 = srcs[p + 3];
        ax0 += x[(size_t)s0 * D + j];
        ax1 += x[(size_t)s1 * D + j];
        ax2 += x[(size_t)s2 * D + j];
        ax3 += x[(size_t)s3 * D + j];
        ae0 += pea[(size_t)p * D + j];
        ae1 += pea[(size_t)(p + 1) * D + j];
        ae2 += pea[(size_t)(p + 2) * D + j];
        ae3 += pea[(size_t)(p + 3) * D + j];
    }
    for (; p < p1; p++) {
        ax0 += x[(size_t)srcs[p] * D + j];
        ae0 += pea[(size_t)p * D + j];
    }
    Sx[(size_t)n * D + j] = (ax0 + ax1) + (ax2 + ax3);
    Se[(size_t)n * D + j] = (ae0 + ae1) + (ae2 + ae3);
}

// ---------------- node update ----------------
__global__ __launch_bounds__(256) void k_node(const float* __restrict__ x,
                                              const float* __restrict__ Sx,
                                              const float* __restrict__ Se,
                                              const float* __restrict__ inv_deg,
                                              const float* __restrict__ Wr,
                                              const float* __restrict__ Wn,
                                              const float* __restrict__ We,
                                              const float* __restrict__ bias,
                                              float* __restrict__ xo, int N, int do_relu) {
    __shared__ float sWr[D * D], sWn[D * D], sWe[D * D];
    __shared__ float rx[4][D], rsx[4][D], rse[4][D];
    int tid = threadIdx.y * 64 + threadIdx.x;
    for (int i = tid; i < D * D; i += 256) {
        sWr[i] = Wr[i];
        sWn[i] = Wn[i];
        sWe[i] = We[i];
    }
    int j = threadIdx.x;
    int ty = threadIdx.y;
    float bj = bias[j];
    for (int g = blockIdx.x; g * 4 < N; g += gridDim.x) {
        int n = g * 4 + ty;
        __syncthreads();
        if (n < N) {
            rx[ty][j]  = x[(size_t)n * D + j];
            rsx[ty][j] = Sx[(size_t)n * D + j];
            rse[ty][j] = Se[(size_t)n * D + j];
        }
        __syncthreads();
        if (n < N) {
            float inv = inv_deg[n];
            float a0 = 0.f, a1 = 0.f, a2 = 0.f;
            #pragma unroll 8
            for (int k = 0; k < D; k++) {
                float xv = rx[ty][k];
                float sv = rsx[ty][k];
                float ev = rse[ty][k];
                a0 += xv * sWr[k * D + j];
                a1 += sv * sWn[k * D + j];
                a2 += ev * sWe[k * D + j];
            }
            float v = a0 + inv * (a1 + a2) + bj;
            xo[(size_t)n * D + j] = do_relu ? fmaxf(v, 0.f) : v;
        }
    }
}

// ---------------- s/t features ----------------
__global__ __launch_bounds__(256) void k_st(const float* __restrict__ x,
                                            const float* __restrict__ Ws, const float* __restrict__ bs,
                                            const float* __restrict__ Wt, const float* __restrict__ bt,
                                            float* __restrict__ sf, float* __restrict__ tf, int N) {
    __shared__ float sWs[D * D], sWt[D * D];
    __shared__ float rx[4][D];
    int tid = threadIdx.y * 64 + threadIdx.x;
    for (int i = tid; i < D * D; i += 256) {
        sWs[i] = Ws[i];
        sWt[i] = Wt[i];
    }
    int j = threadIdx.x;
    int ty = threadIdx.y;
    float bsj = bs[j], btj = bt[j];
    for (int g = blockIdx.x; g * 4 < N; g += gridDim.x) {
        int n = g * 4 + ty;
        __syncthreads();
        if (n < N) rx[ty][j] = x[(size_t)n * D + j];
        __syncthreads();
        if (n < N) {
            float a0 = 0.f, a1 = 0.f;
            #pragma unroll 8
            for (int k = 0; k < D; k++) {
                float xv = rx[ty][k];
                a0 += xv * sWs[k * D + j];
                a1 += xv * sWt[k * D + j];
            }
            sf[(size_t)n * D + j] = a0 + bsj;
            tf[(size_t)n * D + j] = a1 + btj;
        }
    }
}

// ---------------- edge MLP via MFMA (transposed-operand formulation) ----------------
// MODE 0: index = original edge id e. Reads ea_in[e] (sequential), src/dst from
//         original arrays, writes out_p at CSR slot emap[e]=pos[e] (scatter).
// MODE 1: index = CSR slot p. Reads ea_in[p] (sequential), srcA=srcs, dstA=pdst,
//         writes out_p[p] in place (sequential, feeds next k_agg_seq) AND
//         out_e at emap[p]=eids[p] (scatter, the final d_out edge_attr).
template<int MODE>
__global__ __launch_bounds__(256, 2) void k_edge_mfma(
        const float* __restrict__ ea_in,
        const int* __restrict__ srcA, const int* __restrict__ dstA,
        const int* __restrict__ emap,
        const float* __restrict__ sf, const float* __restrict__ tf,
        const float* __restrict__ We, const float* __restrict__ be,
        const float* __restrict__ W1, const float* __restrict__ b1,
        float* __restrict__ out_p, float* __restrict__ out_e, int E) {
    int lane = threadIdx.x & 63;
    int wid  = threadIdx.x >> 6;
    int c = lane & 15;      // edge slot within tile / A-row
    int g = lane >> 4;      // k-group

    // ---- preload weight fragments into registers ----
    s8v weh[4][2], wel[4][2], w1f[4][2];
    #pragma unroll
    for (int nt = 0; nt < 4; nt++) {
        #pragma unroll
        for (int kt = 0; kt < 2; kt++) {
            #pragma unroll
            for (int i = 0; i < 8; i++) {
                int k = 32 * kt + 8 * g + i;            // natural k-order (GEMM1)
                float w = We[k * D + 16 * nt + c];
                unsigned short hb = f2bf(w);
                float hf = bf2f(hb);
                unsigned short lb = f2bf(w - hf);
                weh[nt][kt][i] = (short)hb;
                wel[nt][kt][i] = (short)lb;
            }
            #pragma unroll
            for (int i = 0; i < 8; i++) {
                int k = 32 * kt + 16 * (i >> 2) + 4 * g + (i & 3);  // pi-order (GEMM2)
                w1f[nt][kt][i] = (short)f2bf(W1[k * D + 16 * nt + c]);
            }
        }
    }
    f4 bev[4], b1v[4];
    #pragma unroll
    for (int nt = 0; nt < 4; nt++) {
        bev[nt] = *(const f4*)&be[16 * nt + 4 * g];
        b1v[nt] = *(const f4*)&b1[16 * nt + 4 * g];
    }

    int tiles = (E + 15) >> 4;
    for (int t = blockIdx.x * 4 + wid; t < tiles; t += gridDim.x * 4) {
        int idx = t * 16 + c;
        int ic = idx < E ? idx : E - 1;
        const float* ear = ea_in + (size_t)ic * D;

        // B-frags of GEMM1: lane's own row, natural k-order
        s8v eaf[2];
        #pragma unroll
        for (int kt = 0; kt < 2; kt++) {
            f4 a0 = *(const f4*)&ear[32 * kt + 8 * g];
            f4 a1 = *(const f4*)&ear[32 * kt + 8 * g + 4];
            #pragma unroll
            for (int i = 0; i < 4; i++) {
                eaf[kt][i]     = (short)f2bf(a0[i]);
                eaf[kt][4 + i] = (short)f2bf(a1[i]);
            }
        }

        // GEMM1: h^T = We^T ea^T  (hi + lo products)
        f4 acc[4];
        #pragma unroll
        for (int nt = 0; nt < 4; nt++) acc[nt] = (f4){0.f, 0.f, 0.f, 0.f};
        #pragma unroll
        for (int nt = 0; nt < 4; nt++) {
            #pragma unroll
            for (int kt = 0; kt < 2; kt++) {
                acc[nt] = __builtin_amdgcn_mfma_f32_16x16x32_bf16(weh[nt][kt], eaf[kt], acc[nt], 0, 0, 0);
                acc[nt] = __builtin_amdgcn_mfma_f32_16x16x32_bf16(wel[nt][kt], eaf[kt], acc[nt], 0, 0, 0);
            }
        }

        // epilogue 1: + be + sf[src] + tf[dst], relu, convert to GEMM2 B-frags
        int s = srcA[ic], d = dstA[ic];
        const float* sr = sf + (size_t)s * D;
        const float* tr = tf + (size_t)d * D;
        s8v hf[2];
        #pragma unroll
        for (int nt = 0; nt < 4; nt++) {
            f4 sg = *(const f4*)&sr[16 * nt + 4 * g];
            f4 tg = *(const f4*)&tr[16 * nt + 4 * g];
            f4 h = acc[nt] + bev[nt] + sg + tg;
            #pragma unroll
            for (int r = 0; r < 4; r++) {
                float hv = fmaxf(h[r], 0.f);
                hf[nt >> 1][((nt & 1) << 2) + r] = (short)f2bf(hv);
            }
        }

        // GEMM2: out^T = W1^T h^T  (pi-order on both sides)
        f4 out[4];
        #pragma unroll
        for (int nt = 0; nt < 4; nt++) out[nt] = (f4){0.f, 0.f, 0.f, 0.f};
        #pragma unroll
        for (int nt = 0; nt < 4; nt++) {
            #pragma unroll
            for (int kt = 0; kt < 2; kt++) {
                out[nt] = __builtin_amdgcn_mfma_f32_16x16x32_bf16(w1f[nt][kt], hf[kt], out[nt], 0, 0, 0);
            }
        }

        if (idx < E) {
            #pragma unroll
            for (int nt = 0; nt < 4; nt++) out[nt] += b1v[nt];
            if (MODE == 0) {
                float* orow = out_p + (size_t)emap[ic] * D;   // scatter to CSR slot
                #pragma unroll
                for (int nt = 0; nt < 4; nt++) *(f4*)&orow[16 * nt + 4 * g] = out[nt];
            } else {
                float* orow1 = out_p + (size_t)ic * D;        // in-place, p-order
                float* orow2 = out_e + (size_t)emap[ic] * D;  // final, e-order
                #pragma unroll
                for (int nt = 0; nt < 4; nt++) {
                    *(f4*)&orow1[16 * nt + 4 * g] = out[nt];
                    *(f4*)&orow2[16 * nt + 4 * g] = out[nt];
                }
            }
        }
    }
}

extern "C" void kernel_launch(void* const* d_in, const int* in_sizes, int n_in,
                              void* d_out, int out_size, void* d_ws, size_t ws_size,
                              hipStream_t stream) {
    const float* x0  = (const float*)d_in[0];
    const int*   ei  = (const int*)d_in[1];
    const float* ea0 = (const float*)d_in[2];
    const float* Wr  = (const float*)d_in[3];
    const float* Wn  = (const float*)d_in[4];
    const float* We  = (const float*)d_in[5];
    const float* b   = (const float*)d_in[6];
    const float* EWe = (const float*)d_in[7];
    const float* Ebe = (const float*)d_in[8];
    const float* EWs = (const float*)d_in[9];
    const float* Ebs = (const float*)d_in[10];
    const float* EWt = (const float*)d_in[11];
    const float* Ebt = (const float*)d_in[12];
    const float* EW1 = (const float*)d_in[13];
    const float* Eb1 = (const float*)d_in[14];

    const int N = in_sizes[0] / D;
    const int E = in_sizes[1] / 2;
    const int* src = ei;
    const int* dst = ei + E;

    char* ws = (char*)d_ws;
    size_t off = 0;
    auto alloc = [&](size_t bytes) {
        void* p = ws + off;
        off += (bytes + 255) & ~(size_t)255;
        return p;
    };
    int*   cnt       = (int*)alloc((size_t)N * 4);
    int*   cursor    = (int*)alloc((size_t)N * 4);
    int*   row_start = (int*)alloc((size_t)(N + 1) * 4);
    int*   eids      = (int*)alloc((size_t)E * 4);
    int*   srcs      = (int*)alloc((size_t)E * 4);
    int*   pdst      = (int*)alloc((size_t)E * 4);
    int*   pos       = (int*)alloc((size_t)E * 4);
    float* inv_deg   = (float*)alloc((size_t)N * 4);
    float* Sx        = (float*)alloc((size_t)N * D * 4);
    float* Se        = (float*)alloc((size_t)N * D * 4);
    float* x1        = (float*)alloc((size_t)N * D * 4);
    float* x2        = (float*)alloc((size_t)N * D * 4);
    float* pea       = (float*)alloc((size_t)E * D * 4);  // CSR-ordered edge features
    float* sf = Sx;  // alias: Sx/Se dead after k_node, sf/tf dead after k_edge
    float* tf = Se;

    float* outx  = (float*)d_out;
    float* outea = (float*)d_out + (size_t)N * D;

    hipMemsetAsync(cnt, 0, (size_t)N * 4, stream);
    hipMemsetAsync(cursor, 0, (size_t)N * 4, stream);
    k_count<<<(E + 255) / 256, 256, 0, stream>>>(dst, cnt, E);
    k_scan<<<1, 1024, 0, stream>>>(cnt, row_start, inv_deg, N);
    k_fill<<<(E + 255) / 256, 256, 0, stream>>>(src, dst, row_start, cursor, eids, srcs, pdst, pos, E);

    dim3 b644(64, 4);

    // ---- layer 0 ----
    k_agg_gather<<<(N + 3) / 4, b644, 0, stream>>>(x0, ea0, row_start, eids, srcs, Sx, Se, N);
    k_node<<<2048, b644, 0, stream>>>(x0, Sx, Se, inv_deg, Wr, Wn, We, b, x1, N, 1);
    k_st<<<2048, b644, 0, stream>>>(x1, EWs, Ebs, EWt, Ebt, sf, tf, N);
    k_edge_mfma<0><<<512, 256, 0, stream>>>(ea0, src, dst, pos, sf, tf,
                                            EWe, Ebe, EW1, Eb1, pea, nullptr, E);

    // ---- layer 1 ----
    k_agg_seq<<<(N + 3) / 4, b644, 0, stream>>>(x1, pea, row_start, srcs, Sx, Se, N);
    k_node<<<2048, b644, 0, stream>>>(x1, Sx, Se, inv_deg,
                                      Wr + D * D, Wn + D * D, We + D * D, b + D, x2, N, 1);
    k_st<<<2048, b644, 0, stream>>>(x2, EWs + D * D, Ebs + D, EWt + D * D, Ebt + D, sf, tf, N);
    k_edge_mfma<1><<<512, 256, 0, stream>>>(pea, srcs, pdst, eids, sf, tf,
                                            EWe + D * D, Ebe + D, EW1 + D * D, Eb1 + D,
                                            pea, outea, E);

    // ---- layer 2 ----
    k_agg_seq<<<(N + 3) / 4, b644, 0, stream>>>(x2, pea, row_start, srcs, Sx, Se, N);
    k_node<<<2048, b644, 0, stream>>>(x2, Sx, Se, inv_deg,
                                      Wr + 2 * D * D, Wn + 2 * D * D, We + 2 * D * D, b + 2 * D,
                                      outx, N, 0);
}

// Round 4
// 885.209 us; speedup vs baseline: 1.5699x; 1.1000x over previous
//
#include <hip/hip_runtime.h>

#define D 64
#define LAYERS 3

typedef float  f4  __attribute__((ext_vector_type(4)));
typedef short  s8v __attribute__((ext_vector_type(8)));
typedef short  s4v __attribute__((ext_vector_type(4)));
typedef unsigned short ushort_t;

__device__ __forceinline__ unsigned short f2bf(float x) {
    unsigned int u = __float_as_uint(x);
    unsigned int r = (u + 0x7fffu + ((u >> 16) & 1u)) >> 16;
    return (unsigned short)r;
}
__device__ __forceinline__ float bf2f(unsigned short h) {
    return __uint_as_float(((unsigned int)h) << 16);
}

// ---------------- CSR build ----------------

__global__ void k_count(const int* __restrict__ dst, int* __restrict__ cnt, int E) {
    int e = blockIdx.x * blockDim.x + threadIdx.x;
    if (e < E) atomicAdd(&cnt[dst[e]], 1);
}

__global__ __launch_bounds__(1024) void k_scan(const int* __restrict__ cnt,
                                               int* __restrict__ row_start,
                                               float* __restrict__ inv_deg, int N) {
    __shared__ int buf[1024];
    int tid = threadIdx.x;
    int per = (N + 1023) >> 10;
    int begin = tid * per;
    int end = min(begin + per, N);
    int s = 0;
    for (int i = begin; i < end; i++) s += cnt[i];
    buf[tid] = s;
    __syncthreads();
    for (int off = 1; off < 1024; off <<= 1) {
        int v = 0;
        if (tid >= off) v = buf[tid - off];
        __syncthreads();
        buf[tid] += v;
        __syncthreads();
    }
    int run = buf[tid] - s;
    for (int i = begin; i < end; i++) {
        row_start[i] = run;
        int c = cnt[i];
        inv_deg[i] = 1.0f / (float)(c > 1 ? c : 1);
        run += c;
    }
    if (begin < N && end == N) row_start[N] = run;
}

__global__ void k_fill(const int* __restrict__ src, const int* __restrict__ dst,
                       const int* __restrict__ row_start, int* __restrict__ cursor,
                       int* __restrict__ eids, int* __restrict__ srcs,
                       int* __restrict__ pdst, int* __restrict__ pos, int E) {
    int e = blockIdx.x * blockDim.x + threadIdx.x;
    if (e >= E) return;
    int d = dst[e];
    int p = row_start[d] + atomicAdd(&cursor[d], 1);
    eids[p] = e;
    srcs[p] = src[e];
    pdst[p] = d;
    pos[e] = p;
}

// ---------------- permute ea0 (f32, e-order) -> pea (bf16, CSR p-order) ----------------
// 8 threads per row; sequential 32B reads, 16B scattered-row writes (rows are 128B).
__global__ __launch_bounds__(256) void k_permute(const float* __restrict__ ea,
                                                 const int* __restrict__ pos,
                                                 ushort_t* __restrict__ pea, int E) {
    int t = blockIdx.x * blockDim.x + threadIdx.x;
    int e = t >> 3;
    if (e >= E) return;
    int seg = t & 7;
    const float* rp = ea + (size_t)e * D + seg * 8;
    f4 a0 = *(const f4*)rp;
    f4 a1 = *(const f4*)(rp + 4);
    s8v o;
    #pragma unroll
    for (int i = 0; i < 4; i++) {
        o[i]     = (short)f2bf(a0[i]);
        o[4 + i] = (short)f2bf(a1[i]);
    }
    int p = pos[e];
    *(s8v*)(pea + (size_t)p * D + seg * 8) = o;
}

// ---------------- aggregation: x gathered (small, cache-resident), pea streamed ----------------
__global__ __launch_bounds__(256) void k_agg_seq(const float* __restrict__ x,
                                                 const ushort_t* __restrict__ pea,
                                                 const int* __restrict__ row_start,
                                                 const int* __restrict__ srcs,
                                                 float* __restrict__ Sx, float* __restrict__ Se,
                                                 int N) {
    int n = blockIdx.x * 4 + threadIdx.y;
    if (n >= N) return;
    int j = threadIdx.x;
    int p0 = row_start[n], p1 = row_start[n + 1];
    float ax0 = 0.f, ax1 = 0.f, ax2 = 0.f, ax3 = 0.f;
    float ae0 = 0.f, ae1 = 0.f, ae2 = 0.f, ae3 = 0.f;
    int p = p0;
    for (; p + 4 <= p1; p += 4) {
        int s0 = srcs[p], s1 = srcs[p + 1], s2 = srcs[p + 2], s3 = srcs[p + 3];
        ax0 += x[(size_t)s0 * D + j];
        ax1 += x[(size_t)s1 * D + j];
        ax2 += x[(size_t)s2 * D + j];
        ax3 += x[(size_t)s3 * D + j];
        ae0 += bf2f(pea[(size_t)p * D + j]);
        ae1 += bf2f(pea[(size_t)(p + 1) * D + j]);
        ae2 += bf2f(pea[(size_t)(p + 2) * D + j]);
        ae3 += bf2f(pea[(size_t)(p + 3) * D + j]);
    }
    for (; p < p1; p++) {
        ax0 += x[(size_t)srcs[p] * D + j];
        ae0 += bf2f(pea[(size_t)p * D + j]);
    }
    Sx[(size_t)n * D + j] = (ax0 + ax1) + (ax2 + ax3);
    Se[(size_t)n * D + j] = (ae0 + ae1) + (ae2 + ae3);
}

// ---------------- node update ----------------
__global__ __launch_bounds__(256) void k_node(const float* __restrict__ x,
                                              const float* __restrict__ Sx,
                                              const float* __restrict__ Se,
                                              const float* __restrict__ inv_deg,
                                              const float* __restrict__ Wr,
                                              const float* __restrict__ Wn,
                                              const float* __restrict__ We,
                                              const float* __restrict__ bias,
                                              float* __restrict__ xo, int N, int do_relu) {
    __shared__ float sWr[D * D], sWn[D * D], sWe[D * D];
    __shared__ float rx[4][D], rsx[4][D], rse[4][D];
    int tid = threadIdx.y * 64 + threadIdx.x;
    for (int i = tid; i < D * D; i += 256) {
        sWr[i] = Wr[i];
        sWn[i] = Wn[i];
        sWe[i] = We[i];
    }
    int j = threadIdx.x;
    int ty = threadIdx.y;
    float bj = bias[j];
    for (int g = blockIdx.x; g * 4 < N; g += gridDim.x) {
        int n = g * 4 + ty;
        __syncthreads();
        if (n < N) {
            rx[ty][j]  = x[(size_t)n * D + j];
            rsx[ty][j] = Sx[(size_t)n * D + j];
            rse[ty][j] = Se[(size_t)n * D + j];
        }
        __syncthreads();
        if (n < N) {
            float inv = inv_deg[n];
            float a0 = 0.f, a1 = 0.f, a2 = 0.f;
            #pragma unroll 8
            for (int k = 0; k < D; k++) {
                float xv = rx[ty][k];
                float sv = rsx[ty][k];
                float ev = rse[ty][k];
                a0 += xv * sWr[k * D + j];
                a1 += sv * sWn[k * D + j];
                a2 += ev * sWe[k * D + j];
            }
            float v = a0 + inv * (a1 + a2) + bj;
            xo[(size_t)n * D + j] = do_relu ? fmaxf(v, 0.f) : v;
        }
    }
}

// ---------------- s/t features ----------------
__global__ __launch_bounds__(256) void k_st(const float* __restrict__ x,
                                            const float* __restrict__ Ws, const float* __restrict__ bs,
                                            const float* __restrict__ Wt, const float* __restrict__ bt,
                                            float* __restrict__ sf, float* __restrict__ tf, int N) {
    __shared__ float sWs[D * D], sWt[D * D];
    __shared__ float rx[4][D];
    int tid = threadIdx.y * 64 + threadIdx.x;
    for (int i = tid; i < D * D; i += 256) {
        sWs[i] = Ws[i];
        sWt[i] = Wt[i];
    }
    int j = threadIdx.x;
    int ty = threadIdx.y;
    float bsj = bs[j], btj = bt[j];
    for (int g = blockIdx.x; g * 4 < N; g += gridDim.x) {
        int n = g * 4 + ty;
        __syncthreads();
        if (n < N) rx[ty][j] = x[(size_t)n * D + j];
        __syncthreads();
        if (n < N) {
            float a0 = 0.f, a1 = 0.f;
            #pragma unroll 8
            for (int k = 0; k < D; k++) {
                float xv = rx[ty][k];
                a0 += xv * sWs[k * D + j];
                a1 += xv * sWt[k * D + j];
            }
            sf[(size_t)n * D + j] = a0 + bsj;
            tf[(size_t)n * D + j] = a1 + btj;
        }
    }
}

// ---------------- edge MLP via MFMA, all I/O in CSR p-order, pea in bf16 ----------------
// h^T = We^T @ ea^T ; out^T = W1^T @ h^T via mfma_f32_16x16x32_bf16 (lane's D-col = edge).
// GEMM1 D-frag feeds GEMM2 B-frag in-register via k-permutation baked into W1 prepack.
// Reads ea_in (bf16 p-order), writes out_p (bf16 p-order, feeds next agg / next edge MLP).
// MODE 1 additionally scatter-writes the final f32 edge_attr at emap[p]=eids[p].
// NOTE: ea_in/out_p may alias (in-place p->p rewrite) — no __restrict__ on them.
template<int MODE>
__global__ __launch_bounds__(256, 2) void k_edge_mfma(
        const ushort_t* ea_in,
        const int* __restrict__ srcA, const int* __restrict__ dstA,
        const int* __restrict__ emap,
        const float* __restrict__ sf, const float* __restrict__ tf,
        const float* __restrict__ We, const float* __restrict__ be,
        const float* __restrict__ W1, const float* __restrict__ b1,
        ushort_t* out_p, float* __restrict__ out_e, int E) {
    int lane = threadIdx.x & 63;
    int wid  = threadIdx.x >> 6;
    int c = lane & 15;      // edge slot within tile / A-row
    int g = lane >> 4;      // k-group

    // ---- preload weight fragments into registers ----
    s8v weh[4][2], wel[4][2], w1f[4][2];
    #pragma unroll
    for (int nt = 0; nt < 4; nt++) {
        #pragma unroll
        for (int kt = 0; kt < 2; kt++) {
            #pragma unroll
            for (int i = 0; i < 8; i++) {
                int k = 32 * kt + 8 * g + i;            // natural k-order (GEMM1)
                float w = We[k * D + 16 * nt + c];
                unsigned short hb = f2bf(w);
                float hf = bf2f(hb);
                unsigned short lb = f2bf(w - hf);
                weh[nt][kt][i] = (short)hb;
                wel[nt][kt][i] = (short)lb;
            }
            #pragma unroll
            for (int i = 0; i < 8; i++) {
                int k = 32 * kt + 16 * (i >> 2) + 4 * g + (i & 3);  // pi-order (GEMM2)
                w1f[nt][kt][i] = (short)f2bf(W1[k * D + 16 * nt + c]);
            }
        }
    }
    f4 bev[4], b1v[4];
    #pragma unroll
    for (int nt = 0; nt < 4; nt++) {
        bev[nt] = *(const f4*)&be[16 * nt + 4 * g];
        b1v[nt] = *(const f4*)&b1[16 * nt + 4 * g];
    }

    int tiles = (E + 15) >> 4;
    for (int t = blockIdx.x * 4 + wid; t < tiles; t += gridDim.x * 4) {
        int idx = t * 16 + c;
        int ic = idx < E ? idx : E - 1;
        const ushort_t* ear = ea_in + (size_t)ic * D;

        // B-frags of GEMM1: lane's own bf16 row, natural k-order — direct 16B loads
        s8v eaf[2];
        #pragma unroll
        for (int kt = 0; kt < 2; kt++) {
            eaf[kt] = *(const s8v*)(ear + 32 * kt + 8 * g);
        }

        // GEMM1: h^T = We^T ea^T  (hi + lo products)
        f4 acc[4];
        #pragma unroll
        for (int nt = 0; nt < 4; nt++) acc[nt] = (f4){0.f, 0.f, 0.f, 0.f};
        #pragma unroll
        for (int nt = 0; nt < 4; nt++) {
            #pragma unroll
            for (int kt = 0; kt < 2; kt++) {
                acc[nt] = __builtin_amdgcn_mfma_f32_16x16x32_bf16(weh[nt][kt], eaf[kt], acc[nt], 0, 0, 0);
                acc[nt] = __builtin_amdgcn_mfma_f32_16x16x32_bf16(wel[nt][kt], eaf[kt], acc[nt], 0, 0, 0);
            }
        }

        // epilogue 1: + be + sf[src] + tf[dst], relu, convert to GEMM2 B-frags
        int s = srcA[ic], d = dstA[ic];
        const float* sr = sf + (size_t)s * D;
        const float* tr = tf + (size_t)d * D;
        s8v hf[2];
        #pragma unroll
        for (int nt = 0; nt < 4; nt++) {
            f4 sg = *(const f4*)&sr[16 * nt + 4 * g];
            f4 tg = *(const f4*)&tr[16 * nt + 4 * g];
            f4 h = acc[nt] + bev[nt] + sg + tg;
            #pragma unroll
            for (int r = 0; r < 4; r++) {
                float hv = fmaxf(h[r], 0.f);
                hf[nt >> 1][((nt & 1) << 2) + r] = (short)f2bf(hv);
            }
        }

        // GEMM2: out^T = W1^T h^T  (pi-order on both sides)
        f4 out[4];
        #pragma unroll
        for (int nt = 0; nt < 4; nt++) out[nt] = (f4){0.f, 0.f, 0.f, 0.f};
        #pragma unroll
        for (int nt = 0; nt < 4; nt++) {
            #pragma unroll
            for (int kt = 0; kt < 2; kt++) {
                out[nt] = __builtin_amdgcn_mfma_f32_16x16x32_bf16(w1f[nt][kt], hf[kt], out[nt], 0, 0, 0);
            }
        }

        if (idx < E) {
            #pragma unroll
            for (int nt = 0; nt < 4; nt++) out[nt] += b1v[nt];
            // bf16 p-order write (feeds next agg / next edge layer)
            ushort_t* prow = out_p + (size_t)ic * D;
            #pragma unroll
            for (int nt = 0; nt < 4; nt++) {
                s4v ov;
                #pragma unroll
                for (int r = 0; r < 4; r++) ov[r] = (short)f2bf(out[nt][r]);
                *(s4v*)(prow + 16 * nt + 4 * g) = ov;
            }
            if (MODE == 1) {
                float* orow = out_e + (size_t)emap[ic] * D;  // final f32, e-order
                #pragma unroll
                for (int nt = 0; nt < 4; nt++) *(f4*)&orow[16 * nt + 4 * g] = out[nt];
            }
        }
    }
}

extern "C" void kernel_launch(void* const* d_in, const int* in_sizes, int n_in,
                              void* d_out, int out_size, void* d_ws, size_t ws_size,
                              hipStream_t stream) {
    const float* x0  = (const float*)d_in[0];
    const int*   ei  = (const int*)d_in[1];
    const float* ea0 = (const float*)d_in[2];
    const float* Wr  = (const float*)d_in[3];
    const float* Wn  = (const float*)d_in[4];
    const float* We  = (const float*)d_in[5];
    const float* b   = (const float*)d_in[6];
    const float* EWe = (const float*)d_in[7];
    const float* Ebe = (const float*)d_in[8];
    const float* EWs = (const float*)d_in[9];
    const float* Ebs = (const float*)d_in[10];
    const float* EWt = (const float*)d_in[11];
    const float* Ebt = (const float*)d_in[12];
    const float* EW1 = (const float*)d_in[13];
    const float* Eb1 = (const float*)d_in[14];

    const int N = in_sizes[0] / D;
    const int E = in_sizes[1] / 2;
    const int* src = ei;
    const int* dst = ei + E;

    char* ws = (char*)d_ws;
    size_t off = 0;
    auto alloc = [&](size_t bytes) {
        void* p = ws + off;
        off += (bytes + 255) & ~(size_t)255;
        return p;
    };
    int*      cnt       = (int*)alloc((size_t)N * 4);
    int*      cursor    = (int*)alloc((size_t)N * 4);
    int*      row_start = (int*)alloc((size_t)(N + 1) * 4);
    int*      eids      = (int*)alloc((size_t)E * 4);
    int*      srcs      = (int*)alloc((size_t)E * 4);
    int*      pdst      = (int*)alloc((size_t)E * 4);
    int*      pos       = (int*)alloc((size_t)E * 4);
    float*    inv_deg   = (float*)alloc((size_t)N * 4);
    float*    Sx        = (float*)alloc((size_t)N * D * 4);
    float*    Se        = (float*)alloc((size_t)N * D * 4);
    float*    x1        = (float*)alloc((size_t)N * D * 4);
    float*    x2        = (float*)alloc((size_t)N * D * 4);
    ushort_t* pea       = (ushort_t*)alloc((size_t)E * D * 2);  // CSR-ordered bf16 edge features
    float* sf = Sx;  // alias: Sx/Se dead after k_node, sf/tf dead after k_edge
    float* tf = Se;

    float* outx  = (float*)d_out;
    float* outea = (float*)d_out + (size_t)N * D;

    hipMemsetAsync(cnt, 0, (size_t)N * 4, stream);
    hipMemsetAsync(cursor, 0, (size_t)N * 4, stream);
    k_count<<<(E + 255) / 256, 256, 0, stream>>>(dst, cnt, E);
    k_scan<<<1, 1024, 0, stream>>>(cnt, row_start, inv_deg, N);
    k_fill<<<(E + 255) / 256, 256, 0, stream>>>(src, dst, row_start, cursor, eids, srcs, pdst, pos, E);
    k_permute<<<(E * 8 + 255) / 256, 256, 0, stream>>>(ea0, pos, pea, E);

    dim3 b644(64, 4);

    // ---- layer 0 ----
    k_agg_seq<<<(N + 3) / 4, b644, 0, stream>>>(x0, pea, row_start, srcs, Sx, Se, N);
    k_node<<<2048, b644, 0, stream>>>(x0, Sx, Se, inv_deg, Wr, Wn, We, b, x1, N, 1);
    k_st<<<2048, b644, 0, stream>>>(x1, EWs, Ebs, EWt, Ebt, sf, tf, N);
    k_edge_mfma<0><<<2048, 256, 0, stream>>>(pea, srcs, pdst, eids, sf, tf,
                                             EWe, Ebe, EW1, Eb1, pea, nullptr, E);

    // ---- layer 1 ----
    k_agg_seq<<<(N + 3) / 4, b644, 0, stream>>>(x1, pea, row_start, srcs, Sx, Se, N);
    k_node<<<2048, b644, 0, stream>>>(x1, Sx, Se, inv_deg,
                                      Wr + D * D, Wn + D * D, We + D * D, b + D, x2, N, 1);
    k_st<<<2048, b644, 0, stream>>>(x2, EWs + D * D, Ebs + D, EWt + D * D, Ebt + D, sf, tf, N);
    k_edge_mfma<1><<<2048, 256, 0, stream>>>(pea, srcs, pdst, eids, sf, tf,
                                             EWe + D * D, Ebe + D, EW1 + D * D, Eb1 + D,
                                             pea, outea, E);

    // ---- layer 2 ----
    k_agg_seq<<<(N + 3) / 4, b644, 0, stream>>>(x2, pea, row_start, srcs, Sx, Se, N);
    k_node<<<2048, b644, 0, stream>>>(x2, Sx, Se, inv_deg,
                                      Wr + 2 * D * D, Wn + 2 * D * D, We + 2 * D * D, b + 2 * D,
                                      outx, N, 0);
}